// Round 6
// baseline (396.281 us; speedup 1.0000x reference)
//
#include <hip/hip_runtime.h>
#include <hip/hip_bf16.h>
#include <cstdint>
#include <cstddef>

typedef __bf16 bf16_t;
typedef _Float16 f16_t;
typedef __bf16 bf16x8 __attribute__((ext_vector_type(8)));
typedef float  f32x4  __attribute__((ext_vector_type(4)));

constexpr int kBatch = 4;
constexpr int kT = 4096;
constexpr int kD = 1024;
constexpr int kM = kBatch * kT;     // 16384 rows
constexpr int kCH = kBatch * kD;    // 4096 scan channels
constexpr int kNC = 128;            // scan chunks
constexpr int kL  = kT / kNC;       // 32 steps per chunk
constexpr int LDS_BYTES = 131072;   // 2 bufs x (A 32K + B 32K)

// ---------------------------------------------------------------- helpers
__device__ __forceinline__ void async16(const bf16_t* g, char* l) {
    __builtin_amdgcn_global_load_lds(
        (const __attribute__((address_space(1))) uint32_t*)g,
        (__attribute__((address_space(3))) uint32_t*)l,
        16, 0, 0);
}

__device__ __forceinline__ float fast_sigmoid(float z) {
    return 1.f / (1.f + __expf(-z));
}
__device__ __forceinline__ float fast_tanh(float z) {
    z = fminf(10.f, fmaxf(-10.f, z));
    float e = __expf(2.f * z);
    return (e - 1.f) / (e + 1.f);
}

// ---------------------------------------------------------------- f32 -> bf16 cast (x)
__global__ void cvt_bf16_kernel(const float* __restrict__ in, bf16_t* __restrict__ out, int n8) {
    int i = blockIdx.x * blockDim.x + threadIdx.x;
    if (i >= n8) return;
    const float4* p = reinterpret_cast<const float4*>(in) + 2 * (size_t)i;
    float4 a = p[0], b = p[1];
    bf16x8 o;
    o[0] = (bf16_t)a.x; o[1] = (bf16_t)a.y; o[2] = (bf16_t)a.z; o[3] = (bf16_t)a.w;
    o[4] = (bf16_t)b.x; o[5] = (bf16_t)b.y; o[6] = (bf16_t)b.z; o[7] = (bf16_t)b.w;
    *reinterpret_cast<bf16x8*>(out + 8 * (size_t)i) = o;
}

// merged cast of the 5 weight matrices (each kD*kD) into contiguous wbf
__global__ void cvtw_kernel(const float* __restrict__ w0, const float* __restrict__ w1,
                            const float* __restrict__ w2, const float* __restrict__ w3,
                            const float* __restrict__ w4, bf16_t* __restrict__ out) {
    const int per = kD * kD / 8;
    int i = blockIdx.x * blockDim.x + threadIdx.x;
    int seg = i / per, j = i - seg * per;
    const float* src = seg == 0 ? w0 : seg == 1 ? w1 : seg == 2 ? w2 : seg == 3 ? w3 : w4;
    const float4* p = reinterpret_cast<const float4*>(src) + 2 * (size_t)j;
    float4 a = p[0], b = p[1];
    bf16x8 o;
    o[0] = (bf16_t)a.x; o[1] = (bf16_t)a.y; o[2] = (bf16_t)a.z; o[3] = (bf16_t)a.w;
    o[4] = (bf16_t)b.x; o[5] = (bf16_t)b.y; o[6] = (bf16_t)b.z; o[7] = (bf16_t)b.w;
    *reinterpret_cast<bf16x8*>(out + ((size_t)seg * per + j) * 8) = o;
}

// ---------------------------------------------------------------- 256x256 BK=64 GEMM
// Persistent over TPB consecutive n-tiles (shares the block's A-panel via L2,
// removes generation-packing loss). Per K-tile: [s0 reads(12) | stage A(w+1) |
// MFMA s0(32) | s1 reads(12) | stage B(w+1) | MFMA s1(32) | vmcnt(0) | barrier]
// -- stage issued >=1 MFMA cluster before the drain so L2/HBM latency hides.
// st_16x32 XOR swizzle via pre-swizzled global source; bijective XCD chunking.
// EPI: 0 silu->bf16 | 3 f32 nt | 4 slab0 sigmoid->f16 / slab1 sigmoid->bf16 /
//      slab2 tanh->bf16
template<int EPI, int TPB>
__global__ __launch_bounds__(512, 2)
void gemm256(const bf16_t* __restrict__ A, const bf16_t* __restrict__ Bw,
             const float* __restrict__ bi0, const float* __restrict__ bi1,
             const float* __restrict__ bi2,
             void* __restrict__ out0, void* __restrict__ out1, void* __restrict__ out2,
             int M, int N, int K)
{
    extern __shared__ char lds[];
    const int tid  = threadIdx.x;
    const int lane = tid & 63;
    const int wv   = tid >> 6;
    const int wr   = wv >> 2;      // 0..1  (M waves)
    const int wc   = wv & 3;       // 0..3  (N waves)
    const int l16  = lane & 15;
    const int lhi  = lane >> 4;

    // ---- bijective XCD-chunk swizzle (nwg % 8 == 0 for all our grids) ----
    int bid = blockIdx.y * gridDim.x + blockIdx.x;
    int nwg = gridDim.x * gridDim.y;
    int swz = (bid & 7) * (nwg >> 3) + (bid >> 3);
    int gx  = (N >> 8) / TPB;          // block-columns (each TPB n-tiles)
    int nb0 = (swz % gx) * (TPB << 8);
    int m0  = (swz / gx) << 8;

    // ---- staging per-thread constants (inverse-swizzled global offsets) ----
    auto goff = [&](int chunk) -> size_t {
        int st = chunk >> 6;               // 1KB subtile
        int ri = (chunk >> 2) & 15;        // inner row
        int cp = (chunk & 3) << 3;         // physical inner col (bf16)
        int cl = cp ^ (((ri >> 3) & 1) << 4);  // logical col (involution)
        int gr = ((st >> 1) << 4) + ri;    // row within 128-row half
        int gc = ((st & 1) << 5) + cl;     // col within BK=64
        return (size_t)gr * K + gc;
    };
    const size_t g0 = goff(tid), g1 = goff(512 + tid);
    const int d0 = wv << 10, d1 = 8192 + (wv << 10);   // linear LDS dest (wave base)

    auto STAGE = [&](const bf16_t* G, int row0, int k0, int lds_base) {
        const bf16_t* base = G + (size_t)row0 * K + k0;
        async16(base + g0, lds + lds_base + d0);
        async16(base + g1, lds + lds_base + d1);
    };

    // ---- swizzled ds_read offsets (relative to a half-region base) ----
    auto ldsoff = [&](int r, int c) -> int {
        int ri = r & 15;
        int st = ((r >> 4) << 1) | (c >> 5);
        int cw = (c & 31) ^ (((ri >> 3) & 1) << 4);
        return (st << 10) + (ri << 6) + (cw << 1);
    };
    int offA[4][2], offB[2][2];
#pragma unroll
    for (int m = 0; m < 4; ++m)
#pragma unroll
        for (int s = 0; s < 2; ++s)
            offA[m][s] = ldsoff(wr * 64 + m * 16 + l16, s * 32 + lhi * 8);
#pragma unroll
    for (int n = 0; n < 2; ++n)
#pragma unroll
        for (int s = 0; s < 2; ++s)
            offB[n][s] = ldsoff(wc * 32 + n * 16 + l16, s * 32 + lhi * 8);

    const int NT = K >> 6;   // 16

    for (int it = 0; it < TPB; ++it) {
        const int n0 = nb0 + (it << 8);

        f32x4 acc[8][4];
#pragma unroll
        for (int i = 0; i < 8; ++i)
#pragma unroll
            for (int j = 0; j < 4; ++j)
                acc[i][j] = (f32x4){0.f, 0.f, 0.f, 0.f};

        // ---- prologue: stage tile 0 into buf0 ----
        STAGE(A,  m0,        0, 0);
        STAGE(A,  m0 + 128,  0, 16384);
        STAGE(Bw, n0,        0, 32768);
        STAGE(Bw, n0 + 128,  0, 49152);
        asm volatile("s_waitcnt vmcnt(0)" ::: "memory");
        asm volatile("s_barrier" ::: "memory");

        for (int w = 0; w < NT; ++w) {
            const int bufo  = (w & 1) << 16;
            const int nbufo = bufo ^ 65536;
            const int oA0 = bufo, oA1 = bufo + 16384;
            const int oB0 = bufo + 32768, oB1 = bufo + 49152;
            const int k1 = (w + 1) << 6;

            // ---- s0 reads (12 b128) ----
            bf16x8 aL[4], aH[4], bL[2], bH[2];
#pragma unroll
            for (int m = 0; m < 4; ++m) {
                aL[m] = *reinterpret_cast<const bf16x8*>(lds + oA0 + offA[m][0]);
                aH[m] = *reinterpret_cast<const bf16x8*>(lds + oA1 + offA[m][0]);
            }
#pragma unroll
            for (int n = 0; n < 2; ++n) {
                bL[n] = *reinterpret_cast<const bf16x8*>(lds + oB0 + offB[n][0]);
                bH[n] = *reinterpret_cast<const bf16x8*>(lds + oB1 + offB[n][0]);
            }
            // ---- stage A halves of tile w+1 (into other buffer) ----
            if (w + 1 < NT) {
                STAGE(A, m0,       k1, nbufo);
                STAGE(A, m0 + 128, k1, nbufo + 16384);
            }
            // ---- MFMA s0 (32) ----
            __builtin_amdgcn_s_setprio(1);
#pragma unroll
            for (int m = 0; m < 4; ++m)
#pragma unroll
                for (int n = 0; n < 2; ++n) {
                    acc[m][n]         = __builtin_amdgcn_mfma_f32_16x16x32_bf16(aL[m], bL[n], acc[m][n], 0, 0, 0);
                    acc[m][2 + n]     = __builtin_amdgcn_mfma_f32_16x16x32_bf16(aL[m], bH[n], acc[m][2 + n], 0, 0, 0);
                    acc[4 + m][n]     = __builtin_amdgcn_mfma_f32_16x16x32_bf16(aH[m], bL[n], acc[4 + m][n], 0, 0, 0);
                    acc[4 + m][2 + n] = __builtin_amdgcn_mfma_f32_16x16x32_bf16(aH[m], bH[n], acc[4 + m][2 + n], 0, 0, 0);
                }
            __builtin_amdgcn_s_setprio(0);

            // ---- s1 reads (12 b128) ----
#pragma unroll
            for (int m = 0; m < 4; ++m) {
                aL[m] = *reinterpret_cast<const bf16x8*>(lds + oA0 + offA[m][1]);
                aH[m] = *reinterpret_cast<const bf16x8*>(lds + oA1 + offA[m][1]);
            }
#pragma unroll
            for (int n = 0; n < 2; ++n) {
                bL[n] = *reinterpret_cast<const bf16x8*>(lds + oB0 + offB[n][1]);
                bH[n] = *reinterpret_cast<const bf16x8*>(lds + oB1 + offB[n][1]);
            }
            // ---- stage B halves of tile w+1 ----
            if (w + 1 < NT) {
                STAGE(Bw, n0,       k1, nbufo + 32768);
                STAGE(Bw, n0 + 128, k1, nbufo + 49152);
            }
            // ---- MFMA s1 (32) ----
            __builtin_amdgcn_s_setprio(1);
#pragma unroll
            for (int m = 0; m < 4; ++m)
#pragma unroll
                for (int n = 0; n < 2; ++n) {
                    acc[m][n]         = __builtin_amdgcn_mfma_f32_16x16x32_bf16(aL[m], bL[n], acc[m][n], 0, 0, 0);
                    acc[m][2 + n]     = __builtin_amdgcn_mfma_f32_16x16x32_bf16(aL[m], bH[n], acc[m][2 + n], 0, 0, 0);
                    acc[4 + m][n]     = __builtin_amdgcn_mfma_f32_16x16x32_bf16(aH[m], bL[n], acc[4 + m][n], 0, 0, 0);
                    acc[4 + m][2 + n] = __builtin_amdgcn_mfma_f32_16x16x32_bf16(aH[m], bH[n], acc[4 + m][2 + n], 0, 0, 0);
                }
            __builtin_amdgcn_s_setprio(0);

            if (w + 1 < NT) {
                // stages were issued >=1 MFMA cluster ago -> latency mostly hidden
                asm volatile("s_waitcnt vmcnt(0)" ::: "memory");
                asm volatile("s_barrier" ::: "memory");
            }
        }

        // ---- epilogue: C/D layout col=lane&15, row=(lane>>4)*4+r ----
        const int slab = n0 >> 10;                 // block-uniform (EPI==4)
        const float* bia = (EPI == 4) ? (slab == 0 ? bi0 : slab == 1 ? bi1 : bi2) : nullptr;
#pragma unroll
        for (int j = 0; j < 4; ++j) {
            const int colg = n0 + ((j >> 1) << 7) + wc * 32 + (j & 1) * 16 + l16;
            const int cL = colg & (kD - 1);
            float bs = 0.f;
            if constexpr (EPI == 4) bs = bia[cL];
#pragma unroll
            for (int i = 0; i < 8; ++i) {
                const int rb = m0 + ((i >> 2) << 7) + wr * 64 + (i & 3) * 16 + lhi * 4;
#pragma unroll
                for (int r = 0; r < 4; ++r) {
                    const int rowg = rb + r;
                    const float f = acc[i][j][r];
                    if constexpr (EPI == 0) {
                        float s = f * fast_sigmoid(f);
                        reinterpret_cast<bf16_t*>(out0)[(size_t)rowg * N + colg] = (bf16_t)s;
                    } else if constexpr (EPI == 3) {
                        __builtin_nontemporal_store(f, reinterpret_cast<float*>(out0) + (size_t)rowg * N + colg);
                    } else {  // EPI == 4
                        const size_t idx = (size_t)rowg * kD + cL;
                        if (slab == 0) {
                            __builtin_nontemporal_store((f16_t)fast_sigmoid(f + bs),
                                reinterpret_cast<f16_t*>(out0) + idx);
                        } else if (slab == 1) {
                            __builtin_nontemporal_store((bf16_t)fast_sigmoid(f + bs),
                                reinterpret_cast<bf16_t*>(out1) + idx);
                        } else {
                            __builtin_nontemporal_store((bf16_t)fast_tanh(f + bs),
                                reinterpret_cast<bf16_t*>(out2) + idx);
                        }
                    }
                }
            }
        }
    }
}

// ---------------------------------------------------------------- chunked linear scan
// h_t = a_t*h + beta_t*v_t ; alpha fp16, beta/v bf16.
__global__ void scan_chunk_kernel(const f16_t* __restrict__ alpha,
                                  const bf16_t* __restrict__ beta,
                                  const bf16_t* __restrict__ vv,
                                  float* __restrict__ Aagg,
                                  float* __restrict__ Bagg)
{
    const int u  = blockIdx.x * blockDim.x + threadIdx.x;
    const int ch = u & (kCH - 1);
    const int c  = u >> 12;
    const int b  = ch >> 10;
    const int d  = ch & (kD - 1);
    size_t base = ((size_t)b * kT + (size_t)c * kL) * kD + d;
    float Ac = 1.f, Bc = 0.f;
#pragma unroll 4
    for (int t = 0; t < kL; ++t) {
        float a  = (float)alpha[base];
        float bv = (float)beta[base] * (float)vv[base];
        Ac *= a;
        Bc = a * Bc + bv;
        base += kD;
    }
    Aagg[u] = Ac;
    Bagg[u] = Bc;
}

__global__ void scan_mid_kernel(const float* __restrict__ Aagg,
                                const float* __restrict__ Bagg,
                                float* __restrict__ Hin,
                                float* __restrict__ hlast)
{
    const int ch = blockIdx.x * blockDim.x + threadIdx.x;
    float h = 0.f;
#pragma unroll 8
    for (int c = 0; c < kNC; ++c) {
        Hin[(size_t)c * kCH + ch] = h;
        h = Aagg[(size_t)c * kCH + ch] * h + Bagg[(size_t)c * kCH + ch];
    }
    hlast[ch] = h;
}

__global__ void scan_out_kernel(const f16_t* __restrict__ alpha,
                                const bf16_t* __restrict__ beta,
                                const bf16_t* __restrict__ vv,
                                const float* __restrict__ Hin,
                                bf16_t* __restrict__ cell)
{
    const int u  = blockIdx.x * blockDim.x + threadIdx.x;
    const int ch = u & (kCH - 1);
    const int c  = u >> 12;
    const int b  = ch >> 10;
    const int d  = ch & (kD - 1);
    size_t base = ((size_t)b * kT + (size_t)c * kL) * kD + d;
    float h = Hin[u];
#pragma unroll 4
    for (int t = 0; t < kL; ++t) {
        float a  = (float)alpha[base];
        float bv = (float)beta[base] * (float)vv[base];
        h = a * h + bv;
        float s = 1.f / (1.f + __expf(-h));
        cell[base] = (bf16_t)(h * h * s);
        base += kD;
    }
}

// ---------------------------------------------------------------- launch
extern "C" void kernel_launch(void* const* d_in, const int* in_sizes, int n_in,
                              void* d_out, int out_size, void* d_ws, size_t ws_size,
                              hipStream_t stream)
{
    const float* x     = (const float*)d_in[0];
    const float* W_in  = (const float*)d_in[1];
    const float* W_al  = (const float*)d_in[2];
    const float* b_al  = (const float*)d_in[3];
    const float* W_be  = (const float*)d_in[4];
    const float* b_be  = (const float*)d_in[5];
    const float* W_v   = (const float*)d_in[6];
    const float* b_v   = (const float*)d_in[7];
    const float* W_out = (const float*)d_in[8];

    float* out   = (float*)d_out;
    float* hlast = out + (size_t)kM * kD;

    char* ws = (char*)d_ws;
    size_t off = 0;
    auto alloc = [&](size_t bytes) -> void* {
        void* p = ws + off;
        off += (bytes + 255) & ~(size_t)255;
        return p;
    };
    bf16_t* xbf   = (bf16_t*)alloc((size_t)kM * kD * 2);   // dead after GEMM1 -> cell
    bf16_t* xp    = (bf16_t*)alloc((size_t)kM * kD * 2);   // dead after fused -> aggs
    f16_t*  alpha = (f16_t*) alloc((size_t)kM * kD * 2);
    bf16_t* betab = (bf16_t*)alloc((size_t)kM * kD * 2);
    bf16_t* vb    = (bf16_t*)alloc((size_t)kM * kD * 2);
    bf16_t* wbf   = (bf16_t*)alloc((size_t)5 * kD * kD * 2);

    bf16_t* Winb = wbf;                         // [W_in; W_al; W_be; W_v; W_out]
    bf16_t* Wfus = wbf + 1 * (size_t)kD * kD;   // fused B: rows 0..3071
    bf16_t* Wob  = wbf + 4 * (size_t)kD * kD;

    bf16_t* cell = xbf;
    float*  Aagg = (float*)xp;
    float*  Bagg = Aagg + (size_t)kNC * kCH;
    float*  Hin  = Bagg + (size_t)kNC * kCH;

    hipFuncSetAttribute(reinterpret_cast<const void*>(gemm256<0,1>), hipFuncAttributeMaxDynamicSharedMemorySize, LDS_BYTES);
    hipFuncSetAttribute(reinterpret_cast<const void*>(gemm256<3,1>), hipFuncAttributeMaxDynamicSharedMemorySize, LDS_BYTES);
    hipFuncSetAttribute(reinterpret_cast<const void*>(gemm256<4,3>), hipFuncAttributeMaxDynamicSharedMemorySize, LDS_BYTES);

    // 1) casts to bf16
    {
        int n8 = kM * kD / 8;
        cvt_bf16_kernel<<<(n8 + 255) / 256, 256, 0, stream>>>(x, xbf, n8);
        int wtot = 5 * kD * kD / 8;
        cvtw_kernel<<<(wtot + 255) / 256, 256, 0, stream>>>(W_in, W_al, W_be, W_v, W_out, wbf);
    }

    dim3 grid1(kD / 256, kM / 256);     // (4, 64)  = 256 wgs, 1 n-tile each
    dim3 gridF(1, kM / 256);            // 64 wgs? no: persistent 3-tile: 4 bcol
    gridF = dim3((3 * kD / 256) / 3, kM / 256);   // (4, 64) = 256 wgs, 3 n-tiles each

    // 2) xp = silu(x @ W_in^T)                       [bf16]
    gemm256<0,1><<<grid1, 512, LDS_BYTES, stream>>>(xbf, Winb, nullptr, nullptr, nullptr,
                                                    xp, nullptr, nullptr, kM, kD, kD);
    // 3) fused: alpha=sigmoid(+b_al) f16 | beta=sigmoid(+b_be) bf16 | v=tanh(+b_v) bf16
    gemm256<4,3><<<gridF, 512, LDS_BYTES, stream>>>(xp, Wfus, b_al, b_be, b_v,
                                                    alpha, betab, vb, kM, 3 * kD, kD);
    // 4) chunked scan (bv = beta*v on the fly)
    scan_chunk_kernel<<<kNC * kCH / 256, 256, 0, stream>>>(alpha, betab, vb, Aagg, Bagg);
    scan_mid_kernel<<<kCH / 256, 256, 0, stream>>>(Aagg, Bagg, Hin, hlast);
    scan_out_kernel<<<kNC * kCH / 256, 256, 0, stream>>>(alpha, betab, vb, Hin, cell);

    // 5) output = cell @ W_out^T                     [f32 nt -> d_out]
    gemm256<3,1><<<grid1, 512, LDS_BYTES, stream>>>(cell, Wob, nullptr, nullptr, nullptr,
                                                    out, nullptr, nullptr, kM, kD, kD);
}

// Round 7
// 309.872 us; speedup vs baseline: 1.2789x; 1.2789x over previous
//
#include <hip/hip_runtime.h>
#include <hip/hip_bf16.h>
#include <cstdint>
#include <cstddef>

typedef __bf16 bf16_t;
typedef _Float16 f16_t;
typedef __bf16 bf16x8 __attribute__((ext_vector_type(8)));
typedef float  f32x4  __attribute__((ext_vector_type(4)));
typedef float  f32x16 __attribute__((ext_vector_type(16)));

constexpr int kBatch = 4;
constexpr int kT = 4096;
constexpr int kD = 1024;
constexpr int kM = kBatch * kT;     // 16384 rows
constexpr int kCH = kBatch * kD;    // 4096 scan channels
constexpr int kNC = 128;            // scan chunks
constexpr int kL  = kT / kNC;       // 32 steps per chunk
constexpr int LDS_BYTES = 131072;   // 2 bufs x (A 32K + B 32K)

// ---------------------------------------------------------------- helpers
__device__ __forceinline__ void async16(const bf16_t* g, char* l) {
    __builtin_amdgcn_global_load_lds(
        (const __attribute__((address_space(1))) uint32_t*)g,
        (__attribute__((address_space(3))) uint32_t*)l,
        16, 0, 0);
}

__device__ __forceinline__ float fast_sigmoid(float z) {
    return 1.f / (1.f + __expf(-z));
}
__device__ __forceinline__ float fast_tanh(float z) {
    z = fminf(10.f, fmaxf(-10.f, z));
    float e = __expf(2.f * z);
    return (e - 1.f) / (e + 1.f);
}

// ---------------------------------------------------------------- f32 -> bf16 cast (x)
__global__ void cvt_bf16_kernel(const float* __restrict__ in, bf16_t* __restrict__ out, int n8) {
    int i = blockIdx.x * blockDim.x + threadIdx.x;
    if (i >= n8) return;
    const float4* p = reinterpret_cast<const float4*>(in) + 2 * (size_t)i;
    float4 a = p[0], b = p[1];
    bf16x8 o;
    o[0] = (bf16_t)a.x; o[1] = (bf16_t)a.y; o[2] = (bf16_t)a.z; o[3] = (bf16_t)a.w;
    o[4] = (bf16_t)b.x; o[5] = (bf16_t)b.y; o[6] = (bf16_t)b.z; o[7] = (bf16_t)b.w;
    *reinterpret_cast<bf16x8*>(out + 8 * (size_t)i) = o;
}

// merged cast of the 5 weight matrices (each kD*kD) into contiguous wbf
__global__ void cvtw_kernel(const float* __restrict__ w0, const float* __restrict__ w1,
                            const float* __restrict__ w2, const float* __restrict__ w3,
                            const float* __restrict__ w4, bf16_t* __restrict__ out) {
    const int per = kD * kD / 8;
    int i = blockIdx.x * blockDim.x + threadIdx.x;
    int seg = i / per, j = i - seg * per;
    const float* src = seg == 0 ? w0 : seg == 1 ? w1 : seg == 2 ? w2 : seg == 3 ? w3 : w4;
    const float4* p = reinterpret_cast<const float4*>(src) + 2 * (size_t)j;
    float4 a = p[0], b = p[1];
    bf16x8 o;
    o[0] = (bf16_t)a.x; o[1] = (bf16_t)a.y; o[2] = (bf16_t)a.z; o[3] = (bf16_t)a.w;
    o[4] = (bf16_t)b.x; o[5] = (bf16_t)b.y; o[6] = (bf16_t)b.z; o[7] = (bf16_t)b.w;
    *reinterpret_cast<bf16x8*>(out + ((size_t)seg * per + j) * 8) = o;
}

// ---------------------------------------------------------------- 256x256 BK=64 GEMM
// R5 min-sync schedule (ONE barrier + one late vmcnt(0) per K-tile; stage
// tile w+1 at top of iter w) with 32x32x16 MFMA (halved issue count, +15%
// pipe rate per m119). 8 waves (2M x 4N), per-wave 128x64 out as 4x2 frags
// of 32x32. st_16x32 XOR swizzle via pre-swizzled global source.
// C/D layout (m74/m101): col=lane&31, row=(reg&3)+8*(reg>>2)+4*(lane>>5).
// A/B frags: row/col = lane&31, k-half = lane>>5 (8 bf16 contiguous).
// EPI: 0 silu->bf16 | 3 f32 nt | 4 slab0 sigmoid->f16 / slab1 sigmoid->bf16 /
//      slab2 tanh->bf16  (plain stores for EPI 0/4: outputs re-read soon, LLC)
template<int EPI>
__global__ __launch_bounds__(512, 2)
void gemm256(const bf16_t* __restrict__ A, const bf16_t* __restrict__ Bw,
             const float* __restrict__ bi0, const float* __restrict__ bi1,
             const float* __restrict__ bi2,
             void* __restrict__ out0, void* __restrict__ out1, void* __restrict__ out2,
             int M, int N, int K)
{
    extern __shared__ char lds[];
    const int tid  = threadIdx.x;
    const int lane = tid & 63;
    const int wv   = tid >> 6;
    const int wr   = wv >> 2;      // 0..1  (M waves, 128 rows each)
    const int wc   = wv & 3;       // 0..3  (N waves, 64 cols each)
    const int l32  = lane & 31;
    const int lh   = lane >> 5;    // k-half selector

    // ---- bijective XCD-chunk swizzle (nwg % 8 == 0 for all our grids) ----
    int bid = blockIdx.y * gridDim.x + blockIdx.x;
    int nwg = gridDim.x * gridDim.y;
    int swz = (bid & 7) * (nwg >> 3) + (bid >> 3);
    int gx  = N >> 8;
    int n0  = (swz % gx) << 8;
    int m0  = (swz / gx) << 8;

    // ---- staging per-thread constants (inverse-swizzled global offsets) ----
    auto goff = [&](int chunk) -> size_t {
        int st = chunk >> 6;               // 1KB subtile
        int ri = (chunk >> 2) & 15;        // inner row
        int cp = (chunk & 3) << 3;         // physical inner col (bf16)
        int cl = cp ^ (((ri >> 3) & 1) << 4);  // logical col (involution)
        int gr = ((st >> 1) << 4) + ri;    // row within 128-row half
        int gc = ((st & 1) << 5) + cl;     // col within BK=64
        return (size_t)gr * K + gc;
    };
    const size_t g0 = goff(tid), g1 = goff(512 + tid);
    const int d0 = wv << 10, d1 = 8192 + (wv << 10);   // linear LDS dest (wave base)

    auto STAGE = [&](const bf16_t* G, int row0, int k0, int lds_base) {
        const bf16_t* base = G + (size_t)row0 * K + k0;
        async16(base + g0, lds + lds_base + d0);
        async16(base + g1, lds + lds_base + d1);
    };
    auto STAGE_TILE = [&](int w, int bufo) {
        const int k0 = w << 6;
        STAGE(A,  m0,        k0, bufo);
        STAGE(A,  m0 + 128,  k0, bufo + 16384);
        STAGE(Bw, n0,        k0, bufo + 32768);
        STAGE(Bw, n0 + 128,  k0, bufo + 49152);
    };

    // ---- swizzled ds_read offsets (relative to a half-region base) ----
    auto ldsoff = [&](int r, int c) -> int {
        int ri = r & 15;
        int st = ((r >> 4) << 1) | (c >> 5);
        int cw = (c & 31) ^ (((ri >> 3) & 1) << 4);
        return (st << 10) + (ri << 6) + (cw << 1);
    };
    int offA[4][4], offB[2][4];
#pragma unroll
    for (int m = 0; m < 4; ++m)
#pragma unroll
        for (int ks = 0; ks < 4; ++ks)
            offA[m][ks] = ldsoff(m * 32 + l32, ks * 16 + lh * 8);
#pragma unroll
    for (int n = 0; n < 2; ++n)
#pragma unroll
        for (int ks = 0; ks < 4; ++ks)
            offB[n][ks] = ldsoff(((wc & 1) << 6) + n * 32 + l32, ks * 16 + lh * 8);

    f32x16 acc[4][2];
#pragma unroll
    for (int i = 0; i < 4; ++i)
#pragma unroll
        for (int j = 0; j < 2; ++j)
            acc[i][j] = (f32x16)(0.f);

    const int NT = K >> 6;   // 16

    // ---- prologue: stage tile 0 only ----
    STAGE_TILE(0, 0);
    asm volatile("s_waitcnt vmcnt(0)" ::: "memory");
    asm volatile("s_barrier" ::: "memory");

    for (int w = 0; w < NT; ++w) {
        const int bufo  = (w & 1) << 16;
        const int nbufo = bufo ^ 65536;
        const int aReg = bufo + (wr << 14);                  // A half for this wave
        const int bReg = bufo + 32768 + ((wc >> 1) << 14);   // B half for this wave

        // stage next tile into the buffer whose reads finished last iteration
        if (w + 1 < NT) STAGE_TILE(w + 1, nbufo);

#pragma unroll
        for (int ks = 0; ks < 4; ++ks) {
            bf16x8 aF[4], bF[2];
#pragma unroll
            for (int m = 0; m < 4; ++m)
                aF[m] = *reinterpret_cast<const bf16x8*>(lds + aReg + offA[m][ks]);
#pragma unroll
            for (int n = 0; n < 2; ++n)
                bF[n] = *reinterpret_cast<const bf16x8*>(lds + bReg + offB[n][ks]);
            __builtin_amdgcn_s_setprio(1);
#pragma unroll
            for (int m = 0; m < 4; ++m)
#pragma unroll
                for (int n = 0; n < 2; ++n)
                    acc[m][n] = __builtin_amdgcn_mfma_f32_32x32x16_bf16(aF[m], bF[n], acc[m][n], 0, 0, 0);
            __builtin_amdgcn_s_setprio(0);
        }

        if (w + 1 < NT) {
            // stage of tile w+1 was issued a full K-tile ago -> drain ~free
            asm volatile("s_waitcnt vmcnt(0)" ::: "memory");
            asm volatile("s_barrier" ::: "memory");
        }
    }

    // ---- epilogue: 32x32 C/D layout col=lane&31, row=(reg&3)+8*(reg>>2)+4*lh ----
    const int slab = n0 >> 10;                 // block-uniform (EPI==4)
    const float* bia = (EPI == 4) ? (slab == 0 ? bi0 : slab == 1 ? bi1 : bi2) : nullptr;
#pragma unroll
    for (int nf = 0; nf < 2; ++nf) {
        const int colg = n0 + wc * 64 + nf * 32 + l32;
        const int cL = colg & (kD - 1);
        float bs = 0.f;
        if constexpr (EPI == 4) bs = bia[cL];
#pragma unroll
        for (int mf = 0; mf < 4; ++mf) {
            const int rbase = m0 + wr * 128 + mf * 32 + lh * 4;
#pragma unroll
            for (int rg = 0; rg < 16; ++rg) {
                const int rowg = rbase + (rg & 3) + ((rg >> 2) << 3);
                const float f = acc[mf][nf][rg];
                if constexpr (EPI == 0) {
                    float s = f * fast_sigmoid(f);
                    reinterpret_cast<bf16_t*>(out0)[(size_t)rowg * N + colg] = (bf16_t)s;
                } else if constexpr (EPI == 3) {
                    __builtin_nontemporal_store(f, reinterpret_cast<float*>(out0) + (size_t)rowg * N + colg);
                } else {  // EPI == 4
                    const size_t idx = (size_t)rowg * kD + cL;
                    if (slab == 0) {
                        reinterpret_cast<f16_t*>(out0)[idx] = (f16_t)fast_sigmoid(f + bs);
                    } else if (slab == 1) {
                        reinterpret_cast<bf16_t*>(out1)[idx] = (bf16_t)fast_sigmoid(f + bs);
                    } else {
                        reinterpret_cast<bf16_t*>(out2)[idx] = (bf16_t)fast_tanh(f + bs);
                    }
                }
            }
        }
    }
}

// ---------------------------------------------------------------- chunked linear scan
// h_t = a_t*h + beta_t*v_t ; alpha fp16, beta/v bf16.
__global__ void scan_chunk_kernel(const f16_t* __restrict__ alpha,
                                  const bf16_t* __restrict__ beta,
                                  const bf16_t* __restrict__ vv,
                                  float* __restrict__ Aagg,
                                  float* __restrict__ Bagg)
{
    const int u  = blockIdx.x * blockDim.x + threadIdx.x;
    const int ch = u & (kCH - 1);
    const int c  = u >> 12;
    const int b  = ch >> 10;
    const int d  = ch & (kD - 1);
    size_t base = ((size_t)b * kT + (size_t)c * kL) * kD + d;
    float Ac = 1.f, Bc = 0.f;
#pragma unroll 4
    for (int t = 0; t < kL; ++t) {
        float a  = (float)alpha[base];
        float bv = (float)beta[base] * (float)vv[base];
        Ac *= a;
        Bc = a * Bc + bv;
        base += kD;
    }
    Aagg[u] = Ac;
    Bagg[u] = Bc;
}

__global__ void scan_mid_kernel(const float* __restrict__ Aagg,
                                const float* __restrict__ Bagg,
                                float* __restrict__ Hin,
                                float* __restrict__ hlast)
{
    const int ch = blockIdx.x * blockDim.x + threadIdx.x;
    float h = 0.f;
#pragma unroll 8
    for (int c = 0; c < kNC; ++c) {
        Hin[(size_t)c * kCH + ch] = h;
        h = Aagg[(size_t)c * kCH + ch] * h + Bagg[(size_t)c * kCH + ch];
    }
    hlast[ch] = h;
}

__global__ void scan_out_kernel(const f16_t* __restrict__ alpha,
                                const bf16_t* __restrict__ beta,
                                const bf16_t* __restrict__ vv,
                                const float* __restrict__ Hin,
                                bf16_t* __restrict__ cell)
{
    const int u  = blockIdx.x * blockDim.x + threadIdx.x;
    const int ch = u & (kCH - 1);
    const int c  = u >> 12;
    const int b  = ch >> 10;
    const int d  = ch & (kD - 1);
    size_t base = ((size_t)b * kT + (size_t)c * kL) * kD + d;
    float h = Hin[u];
#pragma unroll 4
    for (int t = 0; t < kL; ++t) {
        float a  = (float)alpha[base];
        float bv = (float)beta[base] * (float)vv[base];
        h = a * h + bv;
        float s = 1.f / (1.f + __expf(-h));
        cell[base] = (bf16_t)(h * h * s);
        base += kD;
    }
}

// ---------------------------------------------------------------- launch
extern "C" void kernel_launch(void* const* d_in, const int* in_sizes, int n_in,
                              void* d_out, int out_size, void* d_ws, size_t ws_size,
                              hipStream_t stream)
{
    const float* x     = (const float*)d_in[0];
    const float* W_in  = (const float*)d_in[1];
    const float* W_al  = (const float*)d_in[2];
    const float* b_al  = (const float*)d_in[3];
    const float* W_be  = (const float*)d_in[4];
    const float* b_be  = (const float*)d_in[5];
    const float* W_v   = (const float*)d_in[6];
    const float* b_v   = (const float*)d_in[7];
    const float* W_out = (const float*)d_in[8];

    float* out   = (float*)d_out;
    float* hlast = out + (size_t)kM * kD;

    char* ws = (char*)d_ws;
    size_t off = 0;
    auto alloc = [&](size_t bytes) -> void* {
        void* p = ws + off;
        off += (bytes + 255) & ~(size_t)255;
        return p;
    };
    bf16_t* xbf   = (bf16_t*)alloc((size_t)kM * kD * 2);   // dead after GEMM1 -> cell
    bf16_t* xp    = (bf16_t*)alloc((size_t)kM * kD * 2);   // dead after fused -> aggs
    f16_t*  alpha = (f16_t*) alloc((size_t)kM * kD * 2);
    bf16_t* betab = (bf16_t*)alloc((size_t)kM * kD * 2);
    bf16_t* vb    = (bf16_t*)alloc((size_t)kM * kD * 2);
    bf16_t* wbf   = (bf16_t*)alloc((size_t)5 * kD * kD * 2);

    bf16_t* Winb = wbf;                         // [W_in; W_al; W_be; W_v; W_out]
    bf16_t* Wfus = wbf + 1 * (size_t)kD * kD;   // fused B: rows 0..3071
    bf16_t* Wob  = wbf + 4 * (size_t)kD * kD;

    bf16_t* cell = xbf;
    float*  Aagg = (float*)xp;
    float*  Bagg = Aagg + (size_t)kNC * kCH;
    float*  Hin  = Bagg + (size_t)kNC * kCH;

    hipFuncSetAttribute(reinterpret_cast<const void*>(gemm256<0>), hipFuncAttributeMaxDynamicSharedMemorySize, LDS_BYTES);
    hipFuncSetAttribute(reinterpret_cast<const void*>(gemm256<3>), hipFuncAttributeMaxDynamicSharedMemorySize, LDS_BYTES);
    hipFuncSetAttribute(reinterpret_cast<const void*>(gemm256<4>), hipFuncAttributeMaxDynamicSharedMemorySize, LDS_BYTES);

    // 1) casts to bf16
    {
        int n8 = kM * kD / 8;
        cvt_bf16_kernel<<<(n8 + 255) / 256, 256, 0, stream>>>(x, xbf, n8);
        int wtot = 5 * kD * kD / 8;
        cvtw_kernel<<<(wtot + 255) / 256, 256, 0, stream>>>(W_in, W_al, W_be, W_v, W_out, wbf);
    }

    dim3 grid1(kD / 256, kM / 256);     // (4, 64)  = 256 wgs
    dim3 gridF(3 * kD / 256, kM / 256); // (12, 64) = 768 wgs

    // 2) xp = silu(x @ W_in^T)                       [bf16]
    gemm256<0><<<grid1, 512, LDS_BYTES, stream>>>(xbf, Winb, nullptr, nullptr, nullptr,
                                                  xp, nullptr, nullptr, kM, kD, kD);
    // 3) fused: alpha=sigmoid(+b_al) f16 | beta=sigmoid(+b_be) bf16 | v=tanh(+b_v) bf16
    gemm256<4><<<gridF, 512, LDS_BYTES, stream>>>(xp, Wfus, b_al, b_be, b_v,
                                                  alpha, betab, vb, kM, 3 * kD, kD);
    // 4) chunked scan (bv = beta*v on the fly)
    scan_chunk_kernel<<<kNC * kCH / 256, 256, 0, stream>>>(alpha, betab, vb, Aagg, Bagg);
    scan_mid_kernel<<<kCH / 256, 256, 0, stream>>>(Aagg, Bagg, Hin, hlast);
    scan_out_kernel<<<kNC * kCH / 256, 256, 0, stream>>>(alpha, betab, vb, Hin, cell);

    // 5) output = cell @ W_out^T                     [f32 nt -> d_out]
    gemm256<3><<<grid1, 512, LDS_BYTES, stream>>>(cell, Wob, nullptr, nullptr, nullptr,
                                                  out, nullptr, nullptr, kM, kD, kD);
}